// Round 4
// baseline (293.590 us; speedup 1.0000x reference)
//
#include <hip/hip_runtime.h>

// Problem constants
#define NB 64
#define NU 9
#define NV 9
#define UV 81
#define HWSZ 9216          // 96*96
#define BLK_PX 256         // pixels per block
#define NWAVE 4

typedef float f32x4 __attribute__((ext_vector_type(4)));

// Cooperative split-plane kernel: one block (4 waves) owns 256 contiguous
// pixels. Each wave processes ~20 of the 81 (u,v) planes with float4 loads
// (16 B/lane -> 1 KB/wave/instr; measured gfx950 data shows achieved HBM BW
// scales with bytes-per-load-instruction: ~2.3 TB/s @4B vs ~6.3 TB/s @16B).
// No max-subtraction needed: |x|<~6 so exp(x)<=403, sums fit fp32 comfortably.
//   global entropy: ln(S) - (sum x e^x)/S,  S = sum e^x   (online, no storage)
//   windowed sums need final argmax -> phase B re-streams (LLC-warm).
__global__ __launch_bounds__(256, 4) void vcn_fused(const float* __restrict__ x,
                                                    float* __restrict__ out) {
    __shared__ float red[NWAVE][4][BLK_PX];   // 16 KB reduce buffer (reused)
    __shared__ int   cent[BLK_PX];            // 1 KB packed window centers

    const int q    = threadIdx.x >> 6;        // wave id 0..3
    const int lane = threadIdx.x & 63;
    const int blk  = blockIdx.x;
    const int b    = blk / 36;                // 36 blocks per batch (9216/256)
    const int hw0  = (blk - b * 36) * BLK_PX;

    const float* xb = x + (size_t)b * UV * HWSZ + hw0;
    const int i0 = (q * UV) >> 2;             // plane partition: 0,20,40,60
    const int i1 = ((q + 1) * UV) >> 2;       // 20,40,60,81

    // ---------------- Phase A: online max/argmax + global-entropy sums ------
    float seg[4] = {0.f, 0.f, 0.f, 0.f};
    float sxe[4] = {0.f, 0.f, 0.f, 0.f};
    float mx[4]  = {-1e30f, -1e30f, -1e30f, -1e30f};
    int   ix[4]  = {0, 0, 0, 0};

    for (int i = i0; i < i1; ++i) {
        f32x4 v = *(const f32x4*)(xb + (size_t)i * HWSZ + lane * 4);
#pragma unroll
        for (int j = 0; j < 4; ++j) {
            float t = v[j];
            float e = __expf(t);
            seg[j] += e;
            sxe[j] = fmaf(t, e, sxe[j]);
            if (t > mx[j]) { mx[j] = t; ix[j] = i; }   // first-occurrence ties
        }
    }
#pragma unroll
    for (int j = 0; j < 4; ++j) {
        int p = lane * 4 + j;
        red[q][0][p] = seg[j];
        red[q][1][p] = sxe[j];
        red[q][2][p] = mx[j];
        red[q][3][p] = __int_as_float(ix[j]);
    }
    __syncthreads();

    // finalize A: wave q owns pixels [64q, 64q+64)
    {
        int p = q * 64 + lane;
        float s = 0.f, sx = 0.f, m = -1e30f;
        int id = 0;
#pragma unroll
        for (int qq = 0; qq < NWAVE; ++qq) {
            s  += red[qq][0][p];
            sx += red[qq][1][p];
            float mm = red[qq][2][p];
            int  ii  = __float_as_int(red[qq][3][p]);
            if (mm > m) { m = mm; id = ii; }   // qq ascending = plane ascending
        }
        float gent = (__logf(s) - sx / s) * 0.22754075f;     // 1/ln(81)
        out[((size_t)b * 4 + 3) * HWSZ + hw0 + p] = gent;
        int ucw = id / NV, vcw = id - ucw * NV;
        cent[p] = ucw * 16 + vcw;
    }
    __syncthreads();

    // ---------------- Phase B: windowed sums (re-stream, LLC-warm) ----------
    int uc[4], vc[4];
#pragma unroll
    for (int j = 0; j < 4; ++j) {
        int c = cent[lane * 4 + j];
        uc[j] = c >> 4;
        vc[j] = c & 15;
    }
    float sel[4] = {0.f, 0.f, 0.f, 0.f};
    float sxl[4] = {0.f, 0.f, 0.f, 0.f};
    float sfx[4] = {0.f, 0.f, 0.f, 0.f};
    float sfy[4] = {0.f, 0.f, 0.f, 0.f};

    int u = i0 / NV;
    int v = i0 - u * NV;
    for (int i = i0; i < i1; ++i) {
        f32x4 vv = *(const f32x4*)(xb + (size_t)i * HWSZ + lane * 4);
        float fu = (float)(u - 4);
        float fv = (float)(v - 4);
#pragma unroll
        for (int j = 0; j < 4; ++j) {
            float t = vv[j];
            float e = __expf(t);
            bool in = ((unsigned)(u - uc[j] + 3) <= 6u) &
                      ((unsigned)(v - vc[j] + 3) <= 6u);
            float e0 = in ? e : 0.f;
            sel[j] += e0;
            sxl[j] = fmaf(t,  e0, sxl[j]);
            sfx[j] = fmaf(fu, e0, sfx[j]);
            sfy[j] = fmaf(fv, e0, sfy[j]);
        }
        ++v;
        if (v == NV) { v = 0; ++u; }
    }
#pragma unroll
    for (int j = 0; j < 4; ++j) {
        int p = lane * 4 + j;
        red[q][0][p] = sel[j];
        red[q][1][p] = sxl[j];
        red[q][2][p] = sfx[j];
        red[q][3][p] = sfy[j];
    }
    __syncthreads();

    // finalize B
    {
        int p = q * 64 + lane;
        float s = 0.f, sx = 0.f, fx = 0.f, fy = 0.f;
#pragma unroll
        for (int qq = 0; qq < NWAVE; ++qq) {
            s  += red[qq][0][p];
            sx += red[qq][1][p];
            fx += red[qq][2][p];
            fy += red[qq][3][p];
        }
        float inv = 1.f / s;
        size_t obase = (size_t)b * 4 * HWSZ + hw0 + p;
        out[obase]             = fx * inv;                          // flow x
        out[obase + HWSZ]      = fy * inv;                          // flow y
        out[obase + 2 * HWSZ]  = (__logf(s) - sx * inv) * 0.25694895f; // 1/ln(49)
    }
}

extern "C" void kernel_launch(void* const* d_in, const int* in_sizes, int n_in,
                              void* d_out, int out_size, void* d_ws, size_t ws_size,
                              hipStream_t stream) {
    const float* x = (const float*)d_in[0];
    float* out = (float*)d_out;
    const int grid = NB * (HWSZ / BLK_PX);   // 64 * 36 = 2304 blocks
    vcn_fused<<<grid, 256, 0, stream>>>(x, out);
}

// Round 6
// 260.039 us; speedup vs baseline: 1.1290x; 1.1290x over previous
//
#include <hip/hip_runtime.h>

// Problem constants
#define NB 64
#define NU 9
#define NV 9
#define UV 81
#define HWSZ 9216          // 96*96
#define TPX 64             // pixels per block = 1 wave

typedef float f32x4 __attribute__((ext_vector_type(4)));

// One wave per block, 64-pixel tile, 21.5 KB private LDS.
// Staging: 21 wave-wide float4 loads (16 B/lane -> 1 KB/wave/instr; measured
// gfx950 scalar-4B-load ceiling is ~2.3 TB/s vs ~6.3 TB/s with 16 B loads).
// A 64-px plane row is 256 B, so one instruction covers 4 plane rows: lane l
// fetches plane 4k+(l>>4), px (l&15)*4 (per-lane global addrs are free-form),
// and ds_write_b128 lands them contiguously as lds[plane*64+px].
// No barriers beyond the single-wave __syncthreads; 7 blocks/CU (LDS-bound)
// give 147 KB of loads in flight per CU -- far beyond the ~10 KB BW-latency
// product, so HBM stays saturated.
__global__ __launch_bounds__(64) void vcn_kernel(const float* __restrict__ x,
                                                 float* __restrict__ out) {
    __shared__ __align__(16) float lds[84 * TPX];   // 21504 B (3 pad rows)

    const int lane = threadIdx.x;      // 0..63
    const int blk  = blockIdx.x;
    const int b    = blk / 144;        // 9216 / 64 = 144 tiles per batch
    const int hw0  = (blk - b * 144) * TPX;

    const float* xb = x + (size_t)b * UV * HWSZ + hw0;

    // ---- Stage 81 plane rows into LDS via 21 float4 loads ----
    const int pj = lane >> 4;          // which of 4 planes this lane serves
    const int px = (lane & 15) * 4;    // pixel offset within the 64-px row
    f32x4* lds4 = (f32x4*)lds;
#pragma unroll
    for (int k = 0; k < 21; ++k) {
        int p = 4 * k + pj;
        p = p > 80 ? 80 : p;           // k=20 tail: lanes 16-63 write pad rows
        f32x4 val = *(const f32x4*)(xb + (size_t)p * HWSZ + px);
        lds4[k * 64 + lane] = val;     // float idx k*256+lane*4 == p*64+px
    }
    __syncthreads();                   // single wave: waitcnt + cheap barrier

    // ---- This pixel's 81-value column into registers ----
    float v[UV];
#pragma unroll
    for (int i = 0; i < UV; ++i) v[i] = lds[i * TPX + lane];

    // ---- Argmax (first occurrence on ties, matching jnp.argmax) ----
    float m = v[0];
    int idx = 0;
#pragma unroll
    for (int i = 1; i < UV; ++i) {
        if (v[i] > m) { m = v[i]; idx = i; }
    }
    int uc = idx / NV;
    int vc = idx - uc * NV;

    // ---- Single pass: global + windowed sums ----
    float seg = 0.f, sxg = 0.f, sel = 0.f, sxl = 0.f, sfx = 0.f, sfy = 0.f;
#pragma unroll
    for (int u = 0; u < NU; ++u) {
        bool ur = (u >= uc - 3) & (u <= uc + 3);
        float fu = (float)(u - 4);
#pragma unroll
        for (int w = 0; w < NV; ++w) {
            float t = v[u * NV + w] - m;
            float e = __expf(t);
            seg += e;
            sxg = fmaf(e, t, sxg);
            bool in = ur & (w >= vc - 3) & (w <= vc + 3);
            float e0 = in ? e : 0.f;
            sel += e0;
            sxl = fmaf(e0, t, sxl);
            sfx = fmaf(e0, fu, sfx);
            sfy = fmaf(e0, (float)(w - 4), sfy);
        }
    }

    const float KLOC = 0.25694895f;    // 1/ln(49)
    const float KGLO = 0.22754075f;    // 1/ln(81)
    float il = 1.f / sel, ig = 1.f / seg;

    float* op = out + (size_t)b * 4 * HWSZ + hw0 + lane;
    op[0 * HWSZ] = sfx * il;
    op[1 * HWSZ] = sfy * il;
    op[2 * HWSZ] = (__logf(sel) - sxl * il) * KLOC;
    op[3 * HWSZ] = (__logf(seg) - sxg * ig) * KGLO;
}

extern "C" void kernel_launch(void* const* d_in, const int* in_sizes, int n_in,
                              void* d_out, int out_size, void* d_ws, size_t ws_size,
                              hipStream_t stream) {
    const float* x = (const float*)d_in[0];
    float* out = (float*)d_out;
    const int grid = NB * (HWSZ / TPX);   // 64 * 144 = 9216 blocks of 1 wave
    vcn_kernel<<<grid, 64, 0, stream>>>(x, out);
}